// Round 12
// baseline (265.441 us; speedup 1.0000x reference)
//
#include <hip/hip_runtime.h>
#include <hip/hip_bf16.h>

// GCN. CSR via 2-pass LDS bucket sort (wave-contiguous global writes only).
// Layer 1 uses agg(xW)=agg(x)W (4 MB table). NEW: nodes processed in
// degree-sorted order (perm) -> zero trip-count divergence inside a wave and
// no block-level degree tail; pooling decoupled into a streaming kernel over
// natural node order. Features bf16, fp32 accumulate.

#define N_NODES 131072
#define N_EDGES 2097152
#define N_GRAPHS 2048
#define IN_CH 12
#define HID 64
#define OUT_CH 4
#define NBUCK 512          // buckets of 256 dst nodes
#define CHUNK 8192         // edges per bucket_kernel block
#define STRIDE 4608        // staging capacity per bucket
#define CSR_STRIDE 5120    // csr capacity per bucket (padded x4)
#define CAP 5120           // place_kernel LDS image capacity (40 KB)
#define NCLS 64            // degree classes (degp/4 clamped)

typedef float f32x2 __attribute__((ext_vector_type(2)));

__device__ __forceinline__ unsigned short f2bf(float f) {
    unsigned u = __float_as_uint(f);
    return (unsigned short)((u + 0x7fffu + ((u >> 16) & 1u)) >> 16);  // RNE
}
__device__ __forceinline__ unsigned pack2bf(float lo, float hi) {
    return (unsigned)f2bf(lo) | ((unsigned)f2bf(hi) << 16);
}
__device__ __forceinline__ float bflo(unsigned v) { return __uint_as_float(v << 16); }
__device__ __forceinline__ float bfhi(unsigned v) { return __uint_as_float(v & 0xFFFF0000u); }

// ---- pass A: LDS bucket sort of edges by dst>>8 into strided staging ----
__global__ __launch_bounds__(1024, 4)
void bucket_kernel(const int* __restrict__ src, const int* __restrict__ dst,
                   int* __restrict__ bucket_count, int* __restrict__ staged) {
    __shared__ int hist[NBUCK];
    __shared__ int lscan[NBUCK];
    __shared__ int gbase[NBUCK];
    __shared__ int cursor[NBUCK];
    __shared__ int sorted[CHUNK];  // 32 KB
    int tid = threadIdx.x;
    int base = blockIdx.x * CHUNK;
    if (tid < NBUCK) { hist[tid] = 0; cursor[tid] = 0; }
    __syncthreads();
    int d8[8], s8[8];
#pragma unroll
    for (int k = 0; k < 8; k++) {
        int i = base + k * 1024 + tid;
        d8[k] = dst[i];
        s8[k] = src[i];
        atomicAdd(&hist[d8[k] >> 8], 1);
    }
    __syncthreads();
    if (tid < NBUCK) lscan[tid] = hist[tid];
    __syncthreads();
    for (int off = 1; off < NBUCK; off <<= 1) {
        int u = (tid < NBUCK && tid >= off) ? lscan[tid - off] : 0;
        __syncthreads();
        if (tid < NBUCK) lscan[tid] += u;
        __syncthreads();
    }
    if (tid < NBUCK) gbase[tid] = atomicAdd(&bucket_count[tid], hist[tid]);
    __syncthreads();
#pragma unroll
    for (int k = 0; k < 8; k++) {
        int b = d8[k] >> 8;
        int start = lscan[b] - hist[b];
        int p = start + atomicAdd(&cursor[b], 1);
        sorted[p] = ((d8[k] & 255) << 17) | s8[k];
    }
    __syncthreads();
    int wid = tid >> 6, lane = tid & 63;
    int g16 = lane >> 4, k16 = lane & 15;
    for (int b0 = wid * 4; b0 < NBUCK; b0 += 64) {
        int b = b0 + g16;
        int cb = hist[b];
        int lbase = lscan[b] - cb;
        int gb = b * STRIDE + gbase[b];
        for (int k = k16; k < cb; k += 16) staged[gb + k] = sorted[lbase + k];
    }
}

// ---- per-bucket: degree count -> padded rowbounds, dinv, class histogram ----
__global__ void count_kernel(const int* __restrict__ bucket_count, const int* __restrict__ staged,
                             int2* __restrict__ rowbounds, float* __restrict__ dinv,
                             int* __restrict__ class_count) {
    __shared__ int cnt[256];
    __shared__ int scn[256];
    __shared__ int clh[NCLS];
    int b = blockIdx.x;
    int tid = threadIdx.x;
    int count = bucket_count[b];
    const int* st = staged + b * STRIDE;
    cnt[tid] = 0;
    if (tid < NCLS) clh[tid] = 0;
    __syncthreads();
    for (int i = tid; i < count; i += 256) atomicAdd(&cnt[(st[i] >> 17) & 255], 1);
    __syncthreads();
    int deg = cnt[tid];
    int degp = (deg + 3) & ~3;  // pad to x4
    scn[tid] = degp;
    int cls = min(degp >> 2, NCLS - 1);
    atomicAdd(&clh[cls], 1);
    __syncthreads();
    for (int off = 1; off < 256; off <<= 1) {
        int u = (tid >= off) ? scn[tid - off] : 0;
        __syncthreads();
        scn[tid] += u;
        __syncthreads();
    }
    int nbase = (b << 8) + tid;
    int gbeg = b * CSR_STRIDE + scn[tid] - degp;
    rowbounds[nbase] = make_int2(gbeg, gbeg + degp);
    dinv[nbase] = rsqrtf((float)deg + 1.0f);
    if (tid < NCLS) atomicAdd(&class_count[tid], clh[tid]);
}

// ---- exclusive scan of 64 class counts -> base + cursor ----
__global__ void class_scan_kernel(const int* __restrict__ class_count,
                                  int* __restrict__ class_cursor) {
    __shared__ int tmp[NCLS];
    int t = threadIdx.x;
    int v = class_count[t];
    tmp[t] = v;
    __syncthreads();
    for (int off = 1; off < NCLS; off <<= 1) {
        int u = (t >= off) ? tmp[t - off] : 0;
        __syncthreads();
        tmp[t] += u;
        __syncthreads();
    }
    class_cursor[t] = tmp[t] - v;  // exclusive
}

// ---- build degree-sorted permutation (LDS-batched reservations) ----
__global__ void perm_kernel(const int2* __restrict__ rowbounds, int* __restrict__ class_cursor,
                            int* __restrict__ perm) {
    __shared__ int clh[NCLS];
    __shared__ int cbase[NCLS];
    __shared__ int ccur[NCLS];
    int tid = threadIdx.x;
    int node = blockIdx.x * 256 + tid;
    if (tid < NCLS) { clh[tid] = 0; ccur[tid] = 0; }
    __syncthreads();
    int2 rb = rowbounds[node];
    int cls = min((rb.y - rb.x) >> 2, NCLS - 1);
    atomicAdd(&clh[cls], 1);
    __syncthreads();
    if (tid < NCLS) cbase[tid] = atomicAdd(&class_cursor[tid], clh[tid]);
    __syncthreads();
    int p = atomicAdd(&ccur[cls], 1);
    perm[cbase[cls] + p] = node;
}

// ---- per-bucket: place records (+zero pads) into CSR via LDS image ----
__global__ void place_kernel(const int* __restrict__ bucket_count, const int* __restrict__ staged,
                             const int2* __restrict__ rowbounds, const float* __restrict__ dinv,
                             int2* __restrict__ csr) {
    __shared__ int loff[256];
    __shared__ int cursor[256];
    __shared__ float ldinv[256];
    __shared__ int totalS;
    __shared__ int2 image[CAP];  // 40 KB
    int b = blockIdx.x;
    int tid = threadIdx.x;
    int nbase = (b << 8) + tid;
    int gb = b * CSR_STRIDE;
    int count = bucket_count[b];
    int2 rb = rowbounds[nbase];
    int lo = rb.x - gb;
    int degp = rb.y - rb.x;
    loff[tid] = lo;
    cursor[tid] = 0;
    ldinv[tid] = dinv[nbase];
    if (tid == 255) totalS = lo + degp;
    __syncthreads();
    const int* st = staged + b * STRIDE;
    for (int i = tid; i < count; i += 256) {
        int rec = st[i];
        int s = rec & 0x1FFFF;
        int dq = (rec >> 17) & 255;
        float norm = dinv[s] * ldinv[dq];
        int p = loff[dq] + atomicAdd(&cursor[dq], 1);
        int2 val = make_int2(s << 6, __float_as_int(norm));  // pre-scaled src offset (x64)
        if (p < CAP) image[p] = val;
        else csr[gb + p] = val;
    }
    __syncthreads();
    for (int p = lo + cursor[tid]; p < lo + degp; p++) {
        int2 z = make_int2(0, 0);
        if (p < CAP) image[p] = z;
        else csr[gb + p] = z;
    }
    __syncthreads();
    int lim = totalS < CAP ? totalS : CAP;
    int2* dstp = csr + gb;
    for (int i = tid; i < lim; i += 256) dstp[i] = image[i];
}

// ---- x fp32[N,12] -> bf16[N,16] zero-padded ----
__global__ void xcast_kernel(const float* __restrict__ x, unsigned short* __restrict__ xb) {
    int n = blockIdx.x * 256 + threadIdx.x;
    const float* xp = x + n * IN_CH;
    unsigned o[8];
#pragma unroll
    for (int k = 0; k < 6; k++) o[k] = pack2bf(xp[2 * k], xp[2 * k + 1]);
    o[6] = 0; o[7] = 0;
    uint4* dst = (uint4*)(xb + n * 16);
    dst[0] = make_uint4(o[0], o[1], o[2], o[3]);
    dst[1] = make_uint4(o[4], o[5], o[6], o[7]);
}

// ---- layer-1 aggregation over x table: wave = 32 perm-sorted nodes ----
__global__ void agg_x_kernel(const int* __restrict__ perm, const int2* __restrict__ rowbounds,
                             const int2* __restrict__ csr, const float* __restrict__ dinv,
                             const unsigned short* __restrict__ xb, float* __restrict__ aggx) {
    int tid = threadIdx.x;
    int w = tid >> 6, lane = tid & 63, sub = lane >> 1, p = lane & 1;
    int qoff = 8 * p;
    int node = perm[(blockIdx.x * 4 + w) * 32 + sub];
    int2 rb = rowbounds[node];
    float dn = dinv[node];
    f32x2 a0[4] = {{0, 0}, {0, 0}, {0, 0}, {0, 0}};
    f32x2 a1[4] = {{0, 0}, {0, 0}, {0, 0}, {0, 0}};
    f32x2 a2[4] = {{0, 0}, {0, 0}, {0, 0}, {0, 0}};
    f32x2 a3[4] = {{0, 0}, {0, 0}, {0, 0}, {0, 0}};
    for (int j = rb.x; j < rb.y; j += 4) {  // uniform trips within wave (sorted)
        int4 e01 = *(const int4*)(csr + j);
        int4 e23 = *(const int4*)(csr + j + 2);
        uint4 u0 = *(const uint4*)(xb + (e01.x >> 2) + qoff);
        uint4 u1 = *(const uint4*)(xb + (e01.z >> 2) + qoff);
        uint4 u2 = *(const uint4*)(xb + (e23.x >> 2) + qoff);
        uint4 u3 = *(const uint4*)(xb + (e23.z >> 2) + qoff);
        float n0 = __int_as_float(e01.y), n1 = __int_as_float(e01.w);
        float n2 = __int_as_float(e23.y), n3 = __int_as_float(e23.w);
        f32x2 nn0 = {n0, n0}, nn1 = {n1, n1}, nn2 = {n2, n2}, nn3 = {n3, n3};
        a0[0] += nn0 * (f32x2){bflo(u0.x), bfhi(u0.x)};
        a0[1] += nn0 * (f32x2){bflo(u0.y), bfhi(u0.y)};
        a0[2] += nn0 * (f32x2){bflo(u0.z), bfhi(u0.z)};
        a0[3] += nn0 * (f32x2){bflo(u0.w), bfhi(u0.w)};
        a1[0] += nn1 * (f32x2){bflo(u1.x), bfhi(u1.x)};
        a1[1] += nn1 * (f32x2){bflo(u1.y), bfhi(u1.y)};
        a1[2] += nn1 * (f32x2){bflo(u1.z), bfhi(u1.z)};
        a1[3] += nn1 * (f32x2){bflo(u1.w), bfhi(u1.w)};
        a2[0] += nn2 * (f32x2){bflo(u2.x), bfhi(u2.x)};
        a2[1] += nn2 * (f32x2){bflo(u2.y), bfhi(u2.y)};
        a2[2] += nn2 * (f32x2){bflo(u2.z), bfhi(u2.z)};
        a2[3] += nn2 * (f32x2){bflo(u2.w), bfhi(u2.w)};
        a3[0] += nn3 * (f32x2){bflo(u3.x), bfhi(u3.x)};
        a3[1] += nn3 * (f32x2){bflo(u3.y), bfhi(u3.y)};
        a3[2] += nn3 * (f32x2){bflo(u3.z), bfhi(u3.z)};
        a3[3] += nn3 * (f32x2){bflo(u3.w), bfhi(u3.w)};
    }
    uint4 su = *(const uint4*)(xb + node * 16 + qoff);
    float dn2 = dn * dn;
    f32x2 nd = {dn2, dn2};
    a0[0] += nd * (f32x2){bflo(su.x), bfhi(su.x)};
    a0[1] += nd * (f32x2){bflo(su.y), bfhi(su.y)};
    a0[2] += nd * (f32x2){bflo(su.z), bfhi(su.z)};
    a0[3] += nd * (f32x2){bflo(su.w), bfhi(su.w)};
    float4 o0, o1;
    f32x2 s0 = (a0[0] + a1[0]) + (a2[0] + a3[0]);
    f32x2 s1 = (a0[1] + a1[1]) + (a2[1] + a3[1]);
    f32x2 s2 = (a0[2] + a1[2]) + (a2[2] + a3[2]);
    f32x2 s3 = (a0[3] + a1[3]) + (a2[3] + a3[3]);
    o0.x = s0[0]; o0.y = s0[1]; o0.z = s1[0]; o0.w = s1[1];
    o1.x = s2[0]; o1.y = s2[1]; o1.z = s3[0]; o1.w = s3[1];
    *(float4*)(aggx + node * 16 + qoff) = o0;       // 64 B row = 1 full line
    *(float4*)(aggx + node * 16 + qoff + 4) = o1;
}

// ---- h1 = relu(aggx[:, :12] @ W1 + b1) -> bf16 ----
__global__ void w1_kernel(const float* __restrict__ aggx, const float* __restrict__ W1,
                          const float* __restrict__ b1, unsigned short* __restrict__ h) {
    __shared__ float sW[IN_CH * HID];
    __shared__ float sA[256];
    int tid = threadIdx.x;
    for (int i = tid; i < IN_CH * HID; i += 256) sW[i] = W1[i];
    int node0 = blockIdx.x * 16;
    sA[tid] = aggx[node0 * 16 + tid];
    __syncthreads();
    int nl = tid >> 4, c4 = (tid & 15) * 4;
    float a0 = 0, a1 = 0, a2 = 0, a3 = 0;
#pragma unroll
    for (int k = 0; k < IN_CH; k++) {
        float av = sA[nl * 16 + k];
        const float* w = &sW[k * HID + c4];
        a0 += av * w[0]; a1 += av * w[1]; a2 += av * w[2]; a3 += av * w[3];
    }
    const float* bb = &b1[c4];
    ushort4 v = {f2bf(fmaxf(a0 + bb[0], 0.0f)), f2bf(fmaxf(a1 + bb[1], 0.0f)),
                 f2bf(fmaxf(a2 + bb[2], 0.0f)), f2bf(fmaxf(a3 + bb[3], 0.0f))};
    *(ushort4*)&h[(node0 + nl) * HID + c4] = v;
}

// ---- h @ W2 : [N,64] @ [64,64], bf16 in/out, fp32 compute ----
__global__ void hw2_kernel(const unsigned short* __restrict__ hin,
                           const float* __restrict__ W2, unsigned short* __restrict__ hout) {
    __shared__ float sW[HID * HID];
    __shared__ __align__(16) float sh[16 * HID];
    int tid = threadIdx.x;
    for (int i = tid; i < HID * HID; i += 256) sW[i] = W2[i];
    int node0 = blockIdx.x * 16;
    {
        uint2 u = *(const uint2*)&hin[node0 * HID + 4 * tid];
        sh[4 * tid + 0] = bflo(u.x); sh[4 * tid + 1] = bfhi(u.x);
        sh[4 * tid + 2] = bflo(u.y); sh[4 * tid + 3] = bfhi(u.y);
    }
    __syncthreads();
    int nl = tid >> 4, c4 = (tid & 15) * 4;
    float a0 = 0, a1 = 0, a2 = 0, a3 = 0;
#pragma unroll 8
    for (int k = 0; k < HID; k++) {
        float hv = sh[nl * HID + k];
        float4 w = *(const float4*)&sW[k * HID + c4];
        a0 += hv * w.x; a1 += hv * w.y; a2 += hv * w.z; a3 += hv * w.w;
    }
    ushort4 v = {f2bf(a0), f2bf(a1), f2bf(a2), f2bf(a3)};
    *(ushort4*)&hout[(node0 + nl) * HID + c4] = v;
}

// ---- layer-2 gather + self loop + bias + relu -> h2 bf16 (perm-sorted waves) ----
__global__ void agg_h_kernel(const int* __restrict__ perm, const int2* __restrict__ rowbounds,
                             const int2* __restrict__ csr, const float* __restrict__ dinv,
                             const unsigned short* __restrict__ h,
                             const float* __restrict__ b, unsigned short* __restrict__ h2) {
    int tid = threadIdx.x;
    int w = tid >> 6, lane = tid & 63, sub = lane >> 3, q = lane & 7;
    int qoff = 8 * q;
    int node = perm[(blockIdx.x * 4 + w) * 8 + sub];
    int2 rb = rowbounds[node];
    float dn = dinv[node];
    f32x2 a0[4] = {{0, 0}, {0, 0}, {0, 0}, {0, 0}};
    f32x2 a1[4] = {{0, 0}, {0, 0}, {0, 0}, {0, 0}};
    f32x2 a2[4] = {{0, 0}, {0, 0}, {0, 0}, {0, 0}};
    f32x2 a3[4] = {{0, 0}, {0, 0}, {0, 0}, {0, 0}};
    for (int j = rb.x; j < rb.y; j += 4) {  // uniform trips within wave (sorted)
        int4 e01 = *(const int4*)(csr + j);
        int4 e23 = *(const int4*)(csr + j + 2);
        uint4 u0 = *(const uint4*)(h + e01.x + qoff);
        uint4 u1 = *(const uint4*)(h + e01.z + qoff);
        uint4 u2 = *(const uint4*)(h + e23.x + qoff);
        uint4 u3 = *(const uint4*)(h + e23.z + qoff);
        float n0 = __int_as_float(e01.y), n1 = __int_as_float(e01.w);
        float n2 = __int_as_float(e23.y), n3 = __int_as_float(e23.w);
        f32x2 nn0 = {n0, n0}, nn1 = {n1, n1}, nn2 = {n2, n2}, nn3 = {n3, n3};
        a0[0] += nn0 * (f32x2){bflo(u0.x), bfhi(u0.x)};
        a0[1] += nn0 * (f32x2){bflo(u0.y), bfhi(u0.y)};
        a0[2] += nn0 * (f32x2){bflo(u0.z), bfhi(u0.z)};
        a0[3] += nn0 * (f32x2){bflo(u0.w), bfhi(u0.w)};
        a1[0] += nn1 * (f32x2){bflo(u1.x), bfhi(u1.x)};
        a1[1] += nn1 * (f32x2){bflo(u1.y), bfhi(u1.y)};
        a1[2] += nn1 * (f32x2){bflo(u1.z), bfhi(u1.z)};
        a1[3] += nn1 * (f32x2){bflo(u1.w), bfhi(u1.w)};
        a2[0] += nn2 * (f32x2){bflo(u2.x), bfhi(u2.x)};
        a2[1] += nn2 * (f32x2){bflo(u2.y), bfhi(u2.y)};
        a2[2] += nn2 * (f32x2){bflo(u2.z), bfhi(u2.z)};
        a2[3] += nn2 * (f32x2){bflo(u2.w), bfhi(u2.w)};
        a3[0] += nn3 * (f32x2){bflo(u3.x), bfhi(u3.x)};
        a3[1] += nn3 * (f32x2){bflo(u3.y), bfhi(u3.y)};
        a3[2] += nn3 * (f32x2){bflo(u3.z), bfhi(u3.z)};
        a3[3] += nn3 * (f32x2){bflo(u3.w), bfhi(u3.w)};
    }
    uint4 su = *(const uint4*)(h + node * HID + qoff);
    float4 b0 = *(const float4*)&b[qoff];
    float4 b1 = *(const float4*)&b[qoff + 4];
    float dn2 = dn * dn;
    f32x2 s0 = (a0[0] + a1[0]) + (a2[0] + a3[0]);
    f32x2 s1 = (a0[1] + a1[1]) + (a2[1] + a3[1]);
    f32x2 s2 = (a0[2] + a1[2]) + (a2[2] + a3[2]);
    f32x2 s3 = (a0[3] + a1[3]) + (a2[3] + a3[3]);
    float v0 = fmaxf(s0[0] + dn2 * bflo(su.x) + b0.x, 0.0f);
    float v1 = fmaxf(s0[1] + dn2 * bfhi(su.x) + b0.y, 0.0f);
    float v2 = fmaxf(s1[0] + dn2 * bflo(su.y) + b0.z, 0.0f);
    float v3 = fmaxf(s1[1] + dn2 * bfhi(su.y) + b0.w, 0.0f);
    float v4 = fmaxf(s2[0] + dn2 * bflo(su.z) + b1.x, 0.0f);
    float v5 = fmaxf(s2[1] + dn2 * bfhi(su.z) + b1.y, 0.0f);
    float v6 = fmaxf(s3[0] + dn2 * bflo(su.w) + b1.z, 0.0f);
    float v7 = fmaxf(s3[1] + dn2 * bfhi(su.w) + b1.w, 0.0f);
    uint4 o;
    o.x = pack2bf(v0, v1); o.y = pack2bf(v2, v3);
    o.z = pack2bf(v4, v5); o.w = pack2bf(v6, v7);
    *(uint4*)(h2 + node * HID + qoff) = o;  // 128 B row = 2 full lines per instr
}

// ---- streaming mean-pool over natural node order (run-length, batch sorted) ----
__global__ void pool_kernel(const unsigned short* __restrict__ h2, const int* __restrict__ batch,
                            float* __restrict__ pool, float* __restrict__ gcnt) {
    __shared__ float red[32][HID];  // 8 KB
    __shared__ int gids[32];
    int tid = threadIdx.x;
    int w = tid >> 6, lane = tid & 63, sub = lane >> 3, q = lane & 7;
    int qoff = 8 * q;
    int node = blockIdx.x * 32 + w * 8 + sub;
    uint4 u = *(const uint4*)(h2 + node * HID + qoff);
    float4 v0 = make_float4(bflo(u.x), bfhi(u.x), bflo(u.y), bfhi(u.y));
    float4 v1 = make_float4(bflo(u.z), bfhi(u.z), bflo(u.w), bfhi(u.w));
    int nl = w * 8 + sub;
    *(float4*)&red[nl][qoff] = v0;
    *(float4*)&red[nl][qoff + 4] = v1;
    if (q == 0) gids[nl] = batch[node];
    __syncthreads();
    if (tid < 64) {
        int c = tid;
        float acc = 0.0f;
        int cur = gids[0], cnt = 0;
        for (int n = 0; n < 32; n++) {
            int g = gids[n];
            if (g != cur) {
                atomicAdd(&pool[cur * HID + c], acc);
                if (c == 0) atomicAdd(&gcnt[cur], (float)cnt);
                acc = 0.0f; cnt = 0; cur = g;
            }
            acc += red[n][c];
            cnt++;
        }
        atomicAdd(&pool[cur * HID + c], acc);
        if (c == 0) atomicAdd(&gcnt[cur], (float)cnt);
    }
}

// ---- final: out = sigmoid((pool/cnt) @ Wfc + bfc) ----
__global__ void final_kernel(const float* __restrict__ pool, const float* __restrict__ gcnt,
                             const float* __restrict__ Wfc, const float* __restrict__ bfc,
                             float* __restrict__ out) {
    int idx = blockIdx.x * 256 + threadIdx.x;
    if (idx >= N_GRAPHS * OUT_CH) return;
    int g = idx >> 2, o = idx & 3;
    float inv = 1.0f / fmaxf(gcnt[g], 1.0f);
    float acc = bfc[o];
#pragma unroll
    for (int k = 0; k < HID; k++) acc += pool[g * HID + k] * inv * Wfc[k * OUT_CH + o];
    out[idx] = 1.0f / (1.0f + expf(-acc));
}

extern "C" void kernel_launch(void* const* d_in, const int* in_sizes, int n_in,
                              void* d_out, int out_size, void* d_ws, size_t ws_size,
                              hipStream_t stream) {
    const float* x   = (const float*)d_in[0];
    const int* eidx  = (const int*)d_in[1];
    const int* batch = (const int*)d_in[2];
    const float* W1  = (const float*)d_in[3];
    const float* b1  = (const float*)d_in[4];
    const float* W2  = (const float*)d_in[5];
    const float* b2  = (const float*)d_in[6];
    const float* Wfc = (const float*)d_in[7];
    const float* bfc = (const float*)d_in[8];
    float* out = (float*)d_out;

    const int* src = eidx;
    const int* dst = eidx + N_EDGES;

    // workspace layout (~79 MB; ws is 256 MB)
    unsigned short* hA = (unsigned short*)d_ws;              // 16 MB bf16 (h1, then h2)
    unsigned short* hB = hA + (size_t)N_NODES * HID;         // 16 MB bf16 (h1@W2)
    int2*  csr    = (int2*)(hB + (size_t)N_NODES * HID);     // 21 MB {src<<6, norm}
    int*   staged = (int*)(csr + (size_t)NBUCK * CSR_STRIDE); // 9.4 MB
    float* dinv   = (float*)(staged + (size_t)NBUCK * STRIDE); // 512 KB
    int2*  rowbounds = (int2*)(dinv + N_NODES);              // 1 MB
    int*   bucket_count = (int*)(rowbounds + N_NODES);       // 2 KB
    int*   class_count  = bucket_count + NBUCK;              // 256 B
    int*   class_cursor = class_count + NCLS;                // 256 B
    int*   perm   = class_cursor + NCLS;                     // 512 KB
    float* pool   = (float*)(perm + N_NODES);                // 512 KB
    float* gcnt   = pool + N_GRAPHS * HID;                   // 8 KB
    unsigned short* xb = (unsigned short*)(gcnt + N_GRAPHS); // 4 MB bf16 [N,16]
    float* aggx   = (float*)(xb + (size_t)N_NODES * 16);     // 8 MB fp32 [N,16]

    hipMemsetAsync(bucket_count, 0, (size_t)(NBUCK + NCLS) * 4, stream);
    hipMemsetAsync(pool, 0, (size_t)(N_GRAPHS * HID + N_GRAPHS) * 4, stream);

    // CSR build + degree-sorted permutation
    bucket_kernel<<<N_EDGES / CHUNK, 1024, 0, stream>>>(src, dst, bucket_count, staged);
    count_kernel<<<NBUCK, 256, 0, stream>>>(bucket_count, staged, rowbounds, dinv, class_count);
    class_scan_kernel<<<1, NCLS, 0, stream>>>(class_count, class_cursor);
    perm_kernel<<<N_NODES / 256, 256, 0, stream>>>(rowbounds, class_cursor, perm);
    place_kernel<<<NBUCK, 256, 0, stream>>>(bucket_count, staged, rowbounds, dinv, csr);

    // layer 1: agg(x) @ W1
    xcast_kernel<<<N_NODES / 256, 256, 0, stream>>>(x, xb);
    agg_x_kernel<<<N_NODES / 128, 256, 0, stream>>>(perm, rowbounds, csr, dinv, xb, aggx);
    w1_kernel<<<N_NODES / 16, 256, 0, stream>>>(aggx, W1, b1, hA);

    // layer 2
    hw2_kernel<<<N_NODES / 16, 256, 0, stream>>>(hA, W2, hB);
    agg_h_kernel<<<N_NODES / 32, 256, 0, stream>>>(perm, rowbounds, csr, dinv, hB, b2, hA);

    // pool + head
    pool_kernel<<<N_NODES / 32, 256, 0, stream>>>(hA, batch, pool, gcnt);
    final_kernel<<<(N_GRAPHS * OUT_CH + 255) / 256, 256, 0, stream>>>(pool, gcnt, Wfc, bfc, out);
}